// Round 2
// baseline (833.490 us; speedup 1.0000x reference)
//
#include <hip/hip_runtime.h>
#include <stdint.h>

// ---------------------------------------------------------------------------
// SimpleGNN_2Layer: 2-layer GCN (PyG GCNConv semantics) on MI355X.
//   h1 = relu( D^-1/2 (A+I) D^-1/2 (x @ W1) + b1 )
//   h2 = relu( D^-1/2 (A+I) D^-1/2 (h1 @ W2) + b2 )
//   out = h2 @ Wl + bl
// Strategy: CSR-by-dst built once per call (count/scan/scatter), reused for
// both layers; project-then-aggregate (32- and 16-wide messages); dinv
// pre/post scaling factorization; fused final dot-product.
// ---------------------------------------------------------------------------

#define TPB 256

// ---- edge dtype auto-detect: int64 (odd 32-bit words all zero) vs int32 ----
__global__ void k_detect(const int* __restrict__ edges, int* __restrict__ flag) {
    int lane = threadIdx.x & 63;
    int v = edges[2 * lane + 1];                 // odd words of first 64 entries
    unsigned long long m = __ballot(v != 0);
    if (lane == 0) flag[0] = (m == 0ULL) ? 1 : 0; // 1 => int64 layout
}

__device__ __forceinline__ int edge_at(const int* __restrict__ e, long long idx, int is64) {
    return e[is64 ? (2 * idx) : idx];            // low word holds value (<2^17)
}

// ---- degree count over dst (no self loop yet) ----
__global__ void k_count(const int* __restrict__ edges, const int* __restrict__ flag,
                        int* __restrict__ deg, long long E) {
    const int is64 = flag[0];
    long long stride = (long long)gridDim.x * blockDim.x;
    for (long long e = (long long)blockIdx.x * blockDim.x + threadIdx.x; e < E; e += stride) {
        int d = edge_at(edges, E + e, is64);
        atomicAdd(&deg[d], 1);
    }
}

// ---- dinv = rsqrt(deg + 1)  (self loop => deg >= 1 always) ----
__global__ void k_dinv(const int* __restrict__ deg, float* __restrict__ dinv, int N) {
    int v = blockIdx.x * blockDim.x + threadIdx.x;
    if (v < N) dinv[v] = rsqrtf((float)(deg[v] + 1));
}

// ---- scan step 1: per-block sums of counts ----
__global__ void k_scan_partial(const int* __restrict__ cnt, int* __restrict__ partial, int N) {
    __shared__ int lds[TPB];
    int i = blockIdx.x * TPB + threadIdx.x;
    lds[threadIdx.x] = (i < N) ? cnt[i] : 0;
    __syncthreads();
    for (int s = TPB / 2; s > 0; s >>= 1) {
        if (threadIdx.x < s) lds[threadIdx.x] += lds[threadIdx.x + s];
        __syncthreads();
    }
    if (threadIdx.x == 0) partial[blockIdx.x] = lds[0];
}

// ---- scan step 2: exclusive scan of partials (NB <= 512), total at [NB] ----
__global__ void k_scan_top(int* __restrict__ partial, int NB) {
    __shared__ int lds[512];
    int t = threadIdx.x;
    int v = (t < NB) ? partial[t] : 0;
    lds[t] = v;
    __syncthreads();
    for (int off = 1; off < 512; off <<= 1) {
        int x = (t >= off) ? lds[t - off] : 0;
        __syncthreads();
        lds[t] += x;
        __syncthreads();
    }
    if (t < NB) partial[t] = lds[t] - v;   // exclusive
    if (t == 0) partial[NB] = lds[511];    // total == E
}

// ---- scan step 3: write row_ptr (exclusive scan of counts) ----
__global__ void k_scan_write(const int* __restrict__ cnt, const int* __restrict__ partial,
                             int* __restrict__ row_ptr, int N, int NB) {
    __shared__ int lds[TPB];
    int i = blockIdx.x * TPB + threadIdx.x;
    int v = (i < N) ? cnt[i] : 0;
    lds[threadIdx.x] = v;
    __syncthreads();
    for (int off = 1; off < TPB; off <<= 1) {
        int x = (threadIdx.x >= off) ? lds[threadIdx.x - off] : 0;
        __syncthreads();
        lds[threadIdx.x] += x;
        __syncthreads();
    }
    if (i < N) row_ptr[i] = partial[blockIdx.x] + lds[threadIdx.x] - v;
    if (i == N) row_ptr[N] = partial[NB];
}

// ---- CSR scatter: col[pos] = src, pos from atomic running fill ----
__global__ void k_scatter(const int* __restrict__ edges, const int* __restrict__ flag,
                          int* __restrict__ fill, int* __restrict__ col, long long E) {
    const int is64 = flag[0];
    long long stride = (long long)gridDim.x * blockDim.x;
    for (long long e = (long long)blockIdx.x * blockDim.x + threadIdx.x; e < E; e += stride) {
        int s = edge_at(edges, e, is64);
        int d = edge_at(edges, E + e, is64);
        int pos = atomicAdd(&fill[d], 1);
        col[pos] = s;
    }
}

// ---- proj1: h1s[v] = (x[v] @ W1) * dinv[v]   (128 -> 32) ----
__global__ void k_proj1(const float* __restrict__ x, const float* __restrict__ W1,
                        const float* __restrict__ dinv, float* __restrict__ h1s, int N) {
    __shared__ float w[128 * 32];
    for (int i = threadIdx.x; i < 128 * 32; i += TPB) w[i] = W1[i];
    __syncthreads();
    int t = blockIdx.x * TPB + threadIdx.x;
    int v = t >> 5, f = t & 31;
    if (v >= N) return;
    const float4* xr = (const float4*)(x + (long long)v * 128);
    float acc = 0.f;
#pragma unroll
    for (int k4 = 0; k4 < 32; k4++) {
        float4 xv = xr[k4];                        // broadcast within 32-lane group
        int k = k4 * 4;
        acc = fmaf(xv.x, w[(k + 0) * 32 + f], acc);
        acc = fmaf(xv.y, w[(k + 1) * 32 + f], acc);
        acc = fmaf(xv.z, w[(k + 2) * 32 + f], acc);
        acc = fmaf(xv.w, w[(k + 3) * 32 + f], acc);
    }
    h1s[(long long)v * 32 + f] = acc * dinv[v];
}

// ---- gather1: out1[v] = relu(dinv[v]*(h1s[v] + sum_in h1s[u]) + b1) ----
__global__ void k_gather1(const float* __restrict__ h1s, const int* __restrict__ col,
                          const int* __restrict__ rp, const float* __restrict__ dinv,
                          const float* __restrict__ b1, float* __restrict__ out1, int N) {
    int t = blockIdx.x * TPB + threadIdx.x;
    int v = t >> 5, f = t & 31;
    if (v >= N) return;
    int beg = rp[v], end = rp[v + 1];
    float s = h1s[(long long)v * 32 + f];          // self loop
    for (int i = beg; i < end; i++) {
        int u = col[i];                            // broadcast load
        s += h1s[(long long)u * 32 + f];           // 128B coalesced per group
    }
    float r = dinv[v] * s + b1[f];
    out1[(long long)v * 32 + f] = r > 0.f ? r : 0.f;
}

// ---- proj2: h2s[v] = (out1[v] @ W2) * dinv[v]   (32 -> 16) ----
__global__ void k_proj2(const float* __restrict__ out1, const float* __restrict__ W2,
                        const float* __restrict__ dinv, float* __restrict__ h2s, int N) {
    __shared__ float w[32 * 16];
    for (int i = threadIdx.x; i < 32 * 16; i += TPB) w[i] = W2[i];
    __syncthreads();
    int t = blockIdx.x * TPB + threadIdx.x;
    int v = t >> 4, f = t & 15;
    if (v >= N) return;
    const float4* xr = (const float4*)(out1 + (long long)v * 32);
    float acc = 0.f;
#pragma unroll
    for (int k4 = 0; k4 < 8; k4++) {
        float4 xv = xr[k4];
        int k = k4 * 4;
        acc = fmaf(xv.x, w[(k + 0) * 16 + f], acc);
        acc = fmaf(xv.y, w[(k + 1) * 16 + f], acc);
        acc = fmaf(xv.z, w[(k + 2) * 16 + f], acc);
        acc = fmaf(xv.w, w[(k + 3) * 16 + f], acc);
    }
    h2s[(long long)v * 16 + f] = acc * dinv[v];
}

// ---- gather2 + relu + final dot with Wl, bias bl ----
__global__ void k_gather2(const float* __restrict__ h2s, const int* __restrict__ col,
                          const int* __restrict__ rp, const float* __restrict__ dinv,
                          const float* __restrict__ b2, const float* __restrict__ Wl,
                          const float* __restrict__ bl, float* __restrict__ out, int N) {
    int t = blockIdx.x * TPB + threadIdx.x;
    int v = t >> 4, f = t & 15;
    if (v >= N) return;
    int beg = rp[v], end = rp[v + 1];
    float s = h2s[(long long)v * 16 + f];          // self loop
    for (int i = beg; i < end; i++) {
        s += h2s[(long long)col[i] * 16 + f];      // 64B coalesced per group
    }
    float r = dinv[v] * s + b2[f];
    r = r > 0.f ? r : 0.f;
    float p = r * Wl[f];
    // reduce across the 16-lane group (xor masks < 16 stay in group)
    p += __shfl_xor(p, 1);
    p += __shfl_xor(p, 2);
    p += __shfl_xor(p, 4);
    p += __shfl_xor(p, 8);
    if (f == 0) out[v] = p + bl[0];
}

// ---------------------------------------------------------------------------
extern "C" void kernel_launch(void* const* d_in, const int* in_sizes, int n_in,
                              void* d_out, int out_size, void* d_ws, size_t ws_size,
                              hipStream_t stream) {
    const float* x    = (const float*)d_in[0];
    const int*   edges= (const int*)d_in[1];     // int32 or int64(low-word) — autodetected
    const float* W1   = (const float*)d_in[2];
    const float* b1   = (const float*)d_in[3];
    const float* W2   = (const float*)d_in[4];
    const float* b2   = (const float*)d_in[5];
    const float* Wl   = (const float*)d_in[6];
    const float* bl   = (const float*)d_in[7];
    float* out = (float*)d_out;

    const int       N = in_sizes[0] / 128;        // 100000
    const long long E = (long long)in_sizes[1] / 2; // 3200000
    const int      NB = (N + TPB - 1) / TPB;      // 391

    // workspace layout (256B aligned slices)
    char* ws = (char*)d_ws;
    size_t off = 0;
    auto carve = [&](size_t bytes) { void* p = ws + off; off = (off + bytes + 255) & ~(size_t)255; return p; };
    int*   flag    = (int*)  carve(sizeof(int));
    int*   deg     = (int*)  carve((size_t)N * 4);
    float* dinv    = (float*)carve((size_t)N * 4);
    int*   row_ptr = (int*)  carve((size_t)(N + 1) * 4);
    int*   fill    = (int*)  carve((size_t)N * 4);
    int*   partial = (int*)  carve((size_t)(NB + 1) * 4);
    int*   col     = (int*)  carve((size_t)E * 4);
    float* h1s     = (float*)carve((size_t)N * 32 * 4);
    float* out1    = (float*)carve((size_t)N * 32 * 4);
    float* h2s     = (float*)carve((size_t)N * 16 * 4);
    (void)ws_size; // total ~47 MB

    // 1. edge dtype detect
    hipLaunchKernelGGL(k_detect, dim3(1), dim3(64), 0, stream, edges, flag);
    // 2. degree count
    hipMemsetAsync(deg, 0, (size_t)N * 4, stream);
    hipLaunchKernelGGL(k_count, dim3(2048), dim3(TPB), 0, stream, edges, flag, deg, E);
    // 3. dinv
    hipLaunchKernelGGL(k_dinv, dim3((N + TPB - 1) / TPB), dim3(TPB), 0, stream, deg, dinv, N);
    // 4. CSR build: scan + scatter
    hipLaunchKernelGGL(k_scan_partial, dim3(NB), dim3(TPB), 0, stream, deg, partial, N);
    hipLaunchKernelGGL(k_scan_top, dim3(1), dim3(512), 0, stream, partial, NB);
    hipLaunchKernelGGL(k_scan_write, dim3(NB), dim3(TPB), 0, stream, deg, partial, row_ptr, N, NB);
    hipMemcpyAsync(fill, row_ptr, (size_t)N * 4, hipMemcpyDeviceToDevice, stream);
    hipLaunchKernelGGL(k_scatter, dim3(2048), dim3(TPB), 0, stream, edges, flag, fill, col, E);
    // 5. layer 1
    hipLaunchKernelGGL(k_proj1, dim3((N * 32 + TPB - 1) / TPB), dim3(TPB), 0, stream, x, W1, dinv, h1s, N);
    hipLaunchKernelGGL(k_gather1, dim3((N + 7) / 8), dim3(TPB), 0, stream, h1s, col, row_ptr, dinv, b1, out1, N);
    // 6. layer 2 + head
    hipLaunchKernelGGL(k_proj2, dim3((N * 16 + TPB - 1) / TPB), dim3(TPB), 0, stream, out1, W2, dinv, h2s, N);
    hipLaunchKernelGGL(k_gather2, dim3((N + 15) / 16), dim3(TPB), 0, stream, h2s, col, row_ptr, dinv, b2, Wl, bl, out, N);
}

// Round 3
// 675.636 us; speedup vs baseline: 1.2336x; 1.2336x over previous
//
#include <hip/hip_runtime.h>
#include <stdint.h>

// ---------------------------------------------------------------------------
// SimpleGNN_2Layer: 2-layer GCN (PyG GCNConv semantics) on MI355X.
//   h1 = relu( D^-1/2 (A+I) D^-1/2 (x @ W1) + b1 )
//   h2 = relu( D^-1/2 (A+I) D^-1/2 (h1 @ W2) + b2 )
//   out = h2 @ Wl + bl
// Round 3: replace atomic random-scatter CSR build (305us, 195MB HBM writes
// for a 12.8MB array) with a 2-pass binned build: bucket radix pass
// (dst>>11, 64 buckets) -> bucket-grouped tmp arrays -> localized
// count/scatter with XCD-contiguous chunk swizzle. tmp aliases h1s/out1.
// ---------------------------------------------------------------------------

#define TPB 256
#define BKT 64
#define BKT_SHIFT 11            // 2048 nodes per bucket
#define NBLK 1024               // chunks for hist/reorder/count2/scatter2

// ---- edge dtype auto-detect: int64 (odd 32-bit words all zero) vs int32 ----
__global__ void k_detect(const int* __restrict__ edges, int* __restrict__ flag) {
    int lane = threadIdx.x & 63;
    int v = edges[2 * lane + 1];                 // odd words of first 64 entries
    unsigned long long m = __ballot(v != 0);
    if (lane == 0) flag[0] = (m == 0ULL) ? 1 : 0; // 1 => int64 layout
}

__device__ __forceinline__ int edge_at(const int* __restrict__ e, long long idx, int is64) {
    return e[is64 ? (2 * idx) : idx];            // low word holds value (<2^17)
}

// ---- pass A: per-chunk bucket histogram, bucket-major output ----
__global__ void k_hist(const int* __restrict__ edges, const int* __restrict__ flag,
                       int* __restrict__ hist, long long E) {
    __shared__ int cnt[BKT];
    if (threadIdx.x < BKT) cnt[threadIdx.x] = 0;
    __syncthreads();
    const int is64 = flag[0];
    const long long chunk = (E + NBLK - 1) / NBLK;
    const long long beg = (long long)blockIdx.x * chunk;
    const long long end = (beg + chunk < E) ? beg + chunk : E;
    for (long long e = beg + threadIdx.x; e < end; e += blockDim.x) {
        int d = edge_at(edges, E + e, is64);
        atomicAdd(&cnt[d >> BKT_SHIFT], 1);
    }
    __syncthreads();
    if (threadIdx.x < BKT) hist[threadIdx.x * NBLK + blockIdx.x] = cnt[threadIdx.x];
}

// ---- pass B: reorder edges into bucket-major tmp arrays ----
__global__ void k_reorder(const int* __restrict__ edges, const int* __restrict__ flag,
                          const int* __restrict__ histoff, int* __restrict__ tmp_s,
                          int* __restrict__ tmp_d, long long E) {
    __shared__ int off[BKT];
    if (threadIdx.x < BKT) off[threadIdx.x] = histoff[threadIdx.x * NBLK + blockIdx.x];
    __syncthreads();
    const int is64 = flag[0];
    const long long chunk = (E + NBLK - 1) / NBLK;
    const long long beg = (long long)blockIdx.x * chunk;
    const long long end = (beg + chunk < E) ? beg + chunk : E;
    for (long long e = beg + threadIdx.x; e < end; e += blockDim.x) {
        int s = edge_at(edges, e, is64);
        int d = edge_at(edges, E + e, is64);
        int pos = atomicAdd(&off[d >> BKT_SHIFT], 1);
        tmp_s[pos] = s;                          // ~256B sequential runs per (blk,bkt)
        tmp_d[pos] = d;
    }
}

// chunk swizzle: same-XCD blocks (blockIdx%8) take contiguous chunks -> the
// deg/fill/col windows they touch stay in one XCD's L2.
__device__ __forceinline__ int xcd_chunk(int b) { return (b & 7) * (NBLK / 8) + (b >> 3); }

// ---- degree count over bucket-grouped dst (localized atomics) ----
__global__ void k_count2(const int* __restrict__ tmp_d, int* __restrict__ deg, long long E) {
    const int blk = xcd_chunk(blockIdx.x);
    const long long chunk = (E + NBLK - 1) / NBLK;
    const long long beg = (long long)blk * chunk;
    const long long end = (beg + chunk < E) ? beg + chunk : E;
    for (long long e = beg + threadIdx.x; e < end; e += blockDim.x)
        atomicAdd(&deg[tmp_d[e]], 1);            // dst within ~2048-node window
}

// ---- dinv = rsqrt(deg + 1)  (self loop => deg >= 1 always) ----
__global__ void k_dinv(const int* __restrict__ deg, float* __restrict__ dinv, int N) {
    int v = blockIdx.x * blockDim.x + threadIdx.x;
    if (v < N) dinv[v] = rsqrtf((float)(deg[v] + 1));
}

// ---- generic scan step 1: per-block sums ----
__global__ void k_scan_partial(const int* __restrict__ cnt, int* __restrict__ partial, int N) {
    __shared__ int lds[TPB];
    int i = blockIdx.x * TPB + threadIdx.x;
    lds[threadIdx.x] = (i < N) ? cnt[i] : 0;
    __syncthreads();
    for (int s = TPB / 2; s > 0; s >>= 1) {
        if (threadIdx.x < s) lds[threadIdx.x] += lds[threadIdx.x + s];
        __syncthreads();
    }
    if (threadIdx.x == 0) partial[blockIdx.x] = lds[0];
}

// ---- generic scan step 2: exclusive scan of partials (NB <= 512) ----
__global__ void k_scan_top(int* __restrict__ partial, int NB) {
    __shared__ int lds[512];
    int t = threadIdx.x;
    int v = (t < NB) ? partial[t] : 0;
    lds[t] = v;
    __syncthreads();
    for (int off = 1; off < 512; off <<= 1) {
        int x = (t >= off) ? lds[t - off] : 0;
        __syncthreads();
        lds[t] += x;
        __syncthreads();
    }
    if (t < NB) partial[t] = lds[t] - v;   // exclusive
    if (t == 0) partial[NB] = lds[511];    // total
}

// ---- generic scan step 3: write exclusive scan ----
__global__ void k_scan_write(const int* __restrict__ cnt, const int* __restrict__ partial,
                             int* __restrict__ outp, int N, int NB) {
    __shared__ int lds[TPB];
    int i = blockIdx.x * TPB + threadIdx.x;
    int v = (i < N) ? cnt[i] : 0;
    lds[threadIdx.x] = v;
    __syncthreads();
    for (int off = 1; off < TPB; off <<= 1) {
        int x = (threadIdx.x >= off) ? lds[threadIdx.x - off] : 0;
        __syncthreads();
        lds[threadIdx.x] += x;
        __syncthreads();
    }
    if (i < N) outp[i] = partial[blockIdx.x] + lds[threadIdx.x] - v;
    if (i == N) outp[N] = partial[NB];
}

// ---- pass C: final CSR scatter from bucket-grouped tmp (localized writes) ----
__global__ void k_scatter2(const int* __restrict__ tmp_s, const int* __restrict__ tmp_d,
                           int* __restrict__ fill, int* __restrict__ col, long long E) {
    const int blk = xcd_chunk(blockIdx.x);
    const long long chunk = (E + NBLK - 1) / NBLK;
    const long long beg = (long long)blk * chunk;
    const long long end = (beg + chunk < E) ? beg + chunk : E;
    for (long long e = beg + threadIdx.x; e < end; e += blockDim.x) {
        int d = tmp_d[e];
        int pos = atomicAdd(&fill[d], 1);        // ~8KB window
        col[pos] = tmp_s[e];                     // ~256KB window, L2-coalesced
    }
}

// ---- proj1: h1s[v] = (x[v] @ W1) * dinv[v]   (128 -> 32) ----
__global__ void k_proj1(const float* __restrict__ x, const float* __restrict__ W1,
                        const float* __restrict__ dinv, float* __restrict__ h1s, int N) {
    __shared__ float w[128 * 32];
    for (int i = threadIdx.x; i < 128 * 32; i += TPB) w[i] = W1[i];
    __syncthreads();
    int t = blockIdx.x * TPB + threadIdx.x;
    int v = t >> 5, f = t & 31;
    if (v >= N) return;
    const float4* xr = (const float4*)(x + (long long)v * 128);
    float acc = 0.f;
#pragma unroll
    for (int k4 = 0; k4 < 32; k4++) {
        float4 xv = xr[k4];                        // broadcast within 32-lane group
        int k = k4 * 4;
        acc = fmaf(xv.x, w[(k + 0) * 32 + f], acc);
        acc = fmaf(xv.y, w[(k + 1) * 32 + f], acc);
        acc = fmaf(xv.z, w[(k + 2) * 32 + f], acc);
        acc = fmaf(xv.w, w[(k + 3) * 32 + f], acc);
    }
    h1s[(long long)v * 32 + f] = acc * dinv[v];
}

// ---- gather1: out1[v] = relu(dinv[v]*(h1s[v] + sum_in h1s[u]) + b1) ----
__global__ void k_gather1(const float* __restrict__ h1s, const int* __restrict__ col,
                          const int* __restrict__ rp, const float* __restrict__ dinv,
                          const float* __restrict__ b1, float* __restrict__ out1, int N) {
    int t = blockIdx.x * TPB + threadIdx.x;
    int v = t >> 5, f = t & 31;
    if (v >= N) return;
    int beg = rp[v], end = rp[v + 1];
    float s = h1s[(long long)v * 32 + f];          // self loop
    for (int i = beg; i < end; i++) {
        int u = col[i];                            // broadcast load
        s += h1s[(long long)u * 32 + f];           // 128B coalesced per group
    }
    float r = dinv[v] * s + b1[f];
    out1[(long long)v * 32 + f] = r > 0.f ? r : 0.f;
}

// ---- proj2: h2s[v] = (out1[v] @ W2) * dinv[v]   (32 -> 16) ----
__global__ void k_proj2(const float* __restrict__ out1, const float* __restrict__ W2,
                        const float* __restrict__ dinv, float* __restrict__ h2s, int N) {
    __shared__ float w[32 * 16];
    for (int i = threadIdx.x; i < 32 * 16; i += TPB) w[i] = W2[i];
    __syncthreads();
    int t = blockIdx.x * TPB + threadIdx.x;
    int v = t >> 4, f = t & 15;
    if (v >= N) return;
    const float4* xr = (const float4*)(out1 + (long long)v * 32);
    float acc = 0.f;
#pragma unroll
    for (int k4 = 0; k4 < 8; k4++) {
        float4 xv = xr[k4];
        int k = k4 * 4;
        acc = fmaf(xv.x, w[(k + 0) * 16 + f], acc);
        acc = fmaf(xv.y, w[(k + 1) * 16 + f], acc);
        acc = fmaf(xv.z, w[(k + 2) * 16 + f], acc);
        acc = fmaf(xv.w, w[(k + 3) * 16 + f], acc);
    }
    h2s[(long long)v * 16 + f] = acc * dinv[v];
}

// ---- gather2 + relu + final dot with Wl, bias bl ----
__global__ void k_gather2(const float* __restrict__ h2s, const int* __restrict__ col,
                          const int* __restrict__ rp, const float* __restrict__ dinv,
                          const float* __restrict__ b2, const float* __restrict__ Wl,
                          const float* __restrict__ bl, float* __restrict__ out, int N) {
    int t = blockIdx.x * TPB + threadIdx.x;
    int v = t >> 4, f = t & 15;
    if (v >= N) return;
    int beg = rp[v], end = rp[v + 1];
    float s = h2s[(long long)v * 16 + f];          // self loop
    for (int i = beg; i < end; i++) {
        s += h2s[(long long)col[i] * 16 + f];      // 64B coalesced per group
    }
    float r = dinv[v] * s + b2[f];
    r = r > 0.f ? r : 0.f;
    float p = r * Wl[f];
    p += __shfl_xor(p, 1);
    p += __shfl_xor(p, 2);
    p += __shfl_xor(p, 4);
    p += __shfl_xor(p, 8);
    if (f == 0) out[v] = p + bl[0];
}

// ---------------------------------------------------------------------------
extern "C" void kernel_launch(void* const* d_in, const int* in_sizes, int n_in,
                              void* d_out, int out_size, void* d_ws, size_t ws_size,
                              hipStream_t stream) {
    const float* x    = (const float*)d_in[0];
    const int*   edges= (const int*)d_in[1];     // int32 or int64(low-word) — autodetected
    const float* W1   = (const float*)d_in[2];
    const float* b1   = (const float*)d_in[3];
    const float* W2   = (const float*)d_in[4];
    const float* b2   = (const float*)d_in[5];
    const float* Wl   = (const float*)d_in[6];
    const float* bl   = (const float*)d_in[7];
    float* out = (float*)d_out;

    const int       N = in_sizes[0] / 128;          // 100000
    const long long E = (long long)in_sizes[1] / 2; // 3200000
    const int      NB = (N + TPB - 1) / TPB;        // 391  (<=512 for scan_top)
    const int   NHIST = BKT * NBLK;                 // 65536
    const int  NB_H   = NHIST / TPB;                // 256  (<=512 for scan_top)

    // workspace layout (256B aligned slices); tmp_s/tmp_d alias h1s/out1
    char* ws = (char*)d_ws;
    size_t off = 0;
    auto carve = [&](size_t bytes) { void* p = ws + off; off = (off + bytes + 255) & ~(size_t)255; return p; };
    int*   flag    = (int*)  carve(sizeof(int));
    int*   deg     = (int*)  carve((size_t)N * 4);
    float* dinv    = (float*)carve((size_t)N * 4);
    int*   row_ptr = (int*)  carve((size_t)(N + 1) * 4);
    int*   fill    = (int*)  carve((size_t)N * 4);
    int*   partial = (int*)  carve((size_t)(NB + 1) * 4);
    int*   partialH= (int*)  carve((size_t)(NB_H + 1) * 4);
    int*   hist    = (int*)  carve((size_t)NHIST * 4);
    int*   histoff = (int*)  carve((size_t)(NHIST + 1) * 4);
    int*   col     = (int*)  carve((size_t)E * 4);
    float* unionA  = (float*)carve((size_t)N * 64 * 4);  // h1s(32)+out1(32) / tmp_s+tmp_d
    float* h2s     = (float*)carve((size_t)N * 16 * 4);
    (void)ws_size; // total ~47 MB

    float* h1s  = unionA;                 // N*32 floats
    float* out1 = unionA + (size_t)N * 32;
    int*   tmp_s = (int*)unionA;          // E ints (12.8MB <= N*32*4)
    int*   tmp_d = (int*)(unionA + (size_t)N * 32);

    // 1. edge dtype detect
    hipLaunchKernelGGL(k_detect, dim3(1), dim3(64), 0, stream, edges, flag);
    // 2. binned CSR build
    hipLaunchKernelGGL(k_hist, dim3(NBLK), dim3(TPB), 0, stream, edges, flag, hist, E);
    hipLaunchKernelGGL(k_scan_partial, dim3(NB_H), dim3(TPB), 0, stream, hist, partialH, NHIST);
    hipLaunchKernelGGL(k_scan_top, dim3(1), dim3(512), 0, stream, partialH, NB_H);
    hipLaunchKernelGGL(k_scan_write, dim3(NB_H), dim3(TPB), 0, stream, hist, partialH, histoff, NHIST, NB_H);
    hipLaunchKernelGGL(k_reorder, dim3(NBLK), dim3(TPB), 0, stream, edges, flag, histoff, tmp_s, tmp_d, E);
    hipMemsetAsync(deg, 0, (size_t)N * 4, stream);
    hipLaunchKernelGGL(k_count2, dim3(NBLK), dim3(TPB), 0, stream, tmp_d, deg, E);
    hipLaunchKernelGGL(k_dinv, dim3((N + TPB - 1) / TPB), dim3(TPB), 0, stream, deg, dinv, N);
    hipLaunchKernelGGL(k_scan_partial, dim3(NB), dim3(TPB), 0, stream, deg, partial, N);
    hipLaunchKernelGGL(k_scan_top, dim3(1), dim3(512), 0, stream, partial, NB);
    hipLaunchKernelGGL(k_scan_write, dim3(NB), dim3(TPB), 0, stream, deg, partial, row_ptr, N, NB);
    hipMemcpyAsync(fill, row_ptr, (size_t)N * 4, hipMemcpyDeviceToDevice, stream);
    hipLaunchKernelGGL(k_scatter2, dim3(NBLK), dim3(TPB), 0, stream, tmp_s, tmp_d, fill, col, E);
    // 3. layer 1 (h1s/out1 reuse tmp region — tmp is dead after scatter2)
    hipLaunchKernelGGL(k_proj1, dim3((N * 32 + TPB - 1) / TPB), dim3(TPB), 0, stream, x, W1, dinv, h1s, N);
    hipLaunchKernelGGL(k_gather1, dim3((N + 7) / 8), dim3(TPB), 0, stream, h1s, col, row_ptr, dinv, b1, out1, N);
    // 4. layer 2 + head
    hipLaunchKernelGGL(k_proj2, dim3((N * 16 + TPB - 1) / TPB), dim3(TPB), 0, stream, out1, W2, dinv, h2s, N);
    hipLaunchKernelGGL(k_gather2, dim3((N + 15) / 16), dim3(TPB), 0, stream, h2s, col, row_ptr, dinv, b2, Wl, bl, out, N);
}

// Round 4
// 522.065 us; speedup vs baseline: 1.5965x; 1.2942x over previous
//
#include <hip/hip_runtime.h>
#include <stdint.h>

// ---------------------------------------------------------------------------
// SimpleGNN_2Layer: 2-layer GCN (PyG GCNConv semantics) on MI355X.
// Round 4:
//  - gather1/gather2: float4 rows + neighbor-slot parallelism (16 lines in
//    flight per wave vs 2) — attack the 152us latency-bound gather.
//  - CSR build diet: packed u32 tmp (dlow<<17|src), bucket from position;
//    detect/dinv/fill-memcpy launches fused away.
// ---------------------------------------------------------------------------

#define TPB 256
#define BKT 64
#define BKT_SHIFT 11            // 2048 nodes per bucket
#define BKT_MASK 2047
#define NBLK 1024               // chunks for hist/reorder/count2/scatter2
#define SRC_BITS 17
#define SRC_MASK 0x1FFFF

__device__ __forceinline__ int edge_at(const int* __restrict__ e, long long idx, int is64) {
    return e[is64 ? (2 * idx) : idx];            // low word holds value (<2^17)
}

// per-block edge dtype detect: int64 => odd 32-bit words of first 64 entries all 0
#define DETECT_IS64(edges)                                            \
    __shared__ int s_is64;                                            \
    if (threadIdx.x < 64) {                                           \
        int v_ = (edges)[2 * threadIdx.x + 1];                        \
        unsigned long long m_ = __ballot(v_ != 0);                    \
        if (threadIdx.x == 0) s_is64 = (m_ == 0ULL) ? 1 : 0;          \
    }

__device__ __forceinline__ void f4add(float4& a, const float4 b) {
    a.x += b.x; a.y += b.y; a.z += b.z; a.w += b.w;
}

// ---- pass A: per-chunk bucket histogram, bucket-major output ----
__global__ void k_hist(const int* __restrict__ edges, int* __restrict__ hist, long long E) {
    __shared__ int cnt[BKT];
    DETECT_IS64(edges);
    if (threadIdx.x < BKT) cnt[threadIdx.x] = 0;
    __syncthreads();
    const int is64 = s_is64;
    const long long chunk = (E + NBLK - 1) / NBLK;
    const long long beg = (long long)blockIdx.x * chunk;
    const long long end = (beg + chunk < E) ? beg + chunk : E;
    for (long long e = beg + threadIdx.x; e < end; e += blockDim.x) {
        int d = edge_at(edges, E + e, is64);
        atomicAdd(&cnt[d >> BKT_SHIFT], 1);
    }
    __syncthreads();
    if (threadIdx.x < BKT) hist[threadIdx.x * NBLK + blockIdx.x] = cnt[threadIdx.x];
}

// ---- pass B: reorder edges into bucket-major packed tmp ----
__global__ void k_reorder(const int* __restrict__ edges, const int* __restrict__ histoff,
                          unsigned int* __restrict__ tmp, long long E) {
    __shared__ int off[BKT];
    DETECT_IS64(edges);
    if (threadIdx.x < BKT) off[threadIdx.x] = histoff[threadIdx.x * NBLK + blockIdx.x];
    __syncthreads();
    const int is64 = s_is64;
    const long long chunk = (E + NBLK - 1) / NBLK;
    const long long beg = (long long)blockIdx.x * chunk;
    const long long end = (beg + chunk < E) ? beg + chunk : E;
    for (long long e = beg + threadIdx.x; e < end; e += blockDim.x) {
        int s = edge_at(edges, e, is64);
        int d = edge_at(edges, E + e, is64);
        int pos = atomicAdd(&off[d >> BKT_SHIFT], 1);
        tmp[pos] = ((unsigned int)(d & BKT_MASK) << SRC_BITS) | (unsigned int)s;
    }
}

// chunk swizzle: same-XCD blocks take contiguous chunks -> deg/fill/col windows local to one XCD L2
__device__ __forceinline__ int xcd_chunk(int b) { return (b & 7) * (NBLK / 8) + (b >> 3); }

// load bucket base positions into LDS; find starting bucket by binary search
__device__ __forceinline__ int find_bucket(const int* base, long long e) {
    int lo = 0, hi = BKT - 1;
    while (lo < hi) { int mid = (lo + hi + 1) >> 1; if (e >= (long long)base[mid]) lo = mid; else hi = mid - 1; }
    return lo;
}

// ---- degree count over bucket-grouped packed dst (localized atomics) ----
__global__ void k_count2(const unsigned int* __restrict__ tmp, const int* __restrict__ histoff,
                         int* __restrict__ deg, long long E) {
    __shared__ int base[BKT + 1];
    if (threadIdx.x <= BKT)
        base[threadIdx.x] = (threadIdx.x < BKT) ? histoff[threadIdx.x * NBLK] : (int)E;
    __syncthreads();
    const int blk = xcd_chunk(blockIdx.x);
    const long long chunk = (E + NBLK - 1) / NBLK;
    const long long beg = (long long)blk * chunk;
    const long long end = (beg + chunk < E) ? beg + chunk : E;
    long long e0 = beg + threadIdx.x;
    if (e0 >= end) return;
    int b = find_bucket(base, e0);
    for (long long e = e0; e < end; e += blockDim.x) {
        while (e >= (long long)base[b + 1]) b++;
        unsigned int p = tmp[e];
        int d = (b << BKT_SHIFT) | (int)(p >> SRC_BITS);
        atomicAdd(&deg[d], 1);
    }
}

// ---- pass C: final CSR scatter from packed tmp (localized atomics/writes) ----
__global__ void k_scatter2(const unsigned int* __restrict__ tmp, const int* __restrict__ histoff,
                           int* __restrict__ fill, int* __restrict__ col, long long E) {
    __shared__ int base[BKT + 1];
    if (threadIdx.x <= BKT)
        base[threadIdx.x] = (threadIdx.x < BKT) ? histoff[threadIdx.x * NBLK] : (int)E;
    __syncthreads();
    const int blk = xcd_chunk(blockIdx.x);
    const long long chunk = (E + NBLK - 1) / NBLK;
    const long long beg = (long long)blk * chunk;
    const long long end = (beg + chunk < E) ? beg + chunk : E;
    long long e0 = beg + threadIdx.x;
    if (e0 >= end) return;
    int b = find_bucket(base, e0);
    for (long long e = e0; e < end; e += blockDim.x) {
        while (e >= (long long)base[b + 1]) b++;
        unsigned int p = tmp[e];
        int srcv = (int)(p & SRC_MASK);
        int d = (b << BKT_SHIFT) | (int)(p >> SRC_BITS);
        int pos = atomicAdd(&fill[d], 1);        // ~8KB window
        col[pos] = srcv;                         // ~256KB window, L2-coalesced
    }
}

// ---- generic scan step 1: per-block sums (+ optional fused dinv) ----
__global__ void k_scan_partial(const int* __restrict__ cnt, int* __restrict__ partial, int N,
                               float* __restrict__ dinv) {
    __shared__ int lds[TPB];
    int i = blockIdx.x * TPB + threadIdx.x;
    int v = (i < N) ? cnt[i] : 0;
    if (dinv && i < N) dinv[i] = rsqrtf((float)(v + 1));   // self loop => deg+1
    lds[threadIdx.x] = v;
    __syncthreads();
    for (int s = TPB / 2; s > 0; s >>= 1) {
        if (threadIdx.x < s) lds[threadIdx.x] += lds[threadIdx.x + s];
        __syncthreads();
    }
    if (threadIdx.x == 0) partial[blockIdx.x] = lds[0];
}

// ---- generic scan step 2: exclusive scan of partials (NB <= 512) ----
__global__ void k_scan_top(int* __restrict__ partial, int NB) {
    __shared__ int lds[512];
    int t = threadIdx.x;
    int v = (t < NB) ? partial[t] : 0;
    lds[t] = v;
    __syncthreads();
    for (int off = 1; off < 512; off <<= 1) {
        int x = (t >= off) ? lds[t - off] : 0;
        __syncthreads();
        lds[t] += x;
        __syncthreads();
    }
    if (t < NB) partial[t] = lds[t] - v;   // exclusive
    if (t == 0) partial[NB] = lds[511];    // total
}

// ---- generic scan step 3: write exclusive scan (+ optional fused fill copy) ----
__global__ void k_scan_write(const int* __restrict__ cnt, const int* __restrict__ partial,
                             int* __restrict__ outp, int* __restrict__ fill, int N, int NB) {
    __shared__ int lds[TPB];
    int i = blockIdx.x * TPB + threadIdx.x;
    int v = (i < N) ? cnt[i] : 0;
    lds[threadIdx.x] = v;
    __syncthreads();
    for (int off = 1; off < TPB; off <<= 1) {
        int x = (threadIdx.x >= off) ? lds[threadIdx.x - off] : 0;
        __syncthreads();
        lds[threadIdx.x] += x;
        __syncthreads();
    }
    if (i < N) {
        int val = partial[blockIdx.x] + lds[threadIdx.x] - v;
        outp[i] = val;
        if (fill) fill[i] = val;
    }
    if (i == N) outp[N] = partial[NB];
}

// ---- proj1: h1s[v] = (x[v] @ W1) * dinv[v]   (128 -> 32) ----
__global__ void k_proj1(const float* __restrict__ x, const float* __restrict__ W1,
                        const float* __restrict__ dinv, float* __restrict__ h1s, int N) {
    __shared__ float w[128 * 32];
    for (int i = threadIdx.x; i < 128 * 32; i += TPB) w[i] = W1[i];
    __syncthreads();
    int t = blockIdx.x * TPB + threadIdx.x;
    int v = t >> 5, f = t & 31;
    if (v >= N) return;
    const float4* xr = (const float4*)(x + (long long)v * 128);
    float acc = 0.f;
#pragma unroll
    for (int k4 = 0; k4 < 32; k4++) {
        float4 xv = xr[k4];                        // broadcast within 32-lane group
        int k = k4 * 4;
        acc = fmaf(xv.x, w[(k + 0) * 32 + f], acc);
        acc = fmaf(xv.y, w[(k + 1) * 32 + f], acc);
        acc = fmaf(xv.z, w[(k + 2) * 32 + f], acc);
        acc = fmaf(xv.w, w[(k + 3) * 32 + f], acc);
    }
    h1s[(long long)v * 32 + f] = acc * dinv[v];
}

// ---- gather1: out1[v] = relu(dinv[v]*(h1s[v] + sum_in h1s[u]) + b1) ----
// 32 lanes/node = 4 neighbor-slots x 8 float4-lanes; unroll 2 -> 16 lines in flight/wave
__global__ void k_gather1(const float* __restrict__ h1s, const int* __restrict__ col,
                          const int* __restrict__ rp, const float* __restrict__ dinv,
                          const float* __restrict__ b1, float* __restrict__ out1, int N) {
    int t = blockIdx.x * TPB + threadIdx.x;
    int v = t >> 5;
    if (v >= N) return;
    int l32 = threadIdx.x & 31;
    int slot = l32 >> 3;                 // 0..3
    int f4 = l32 & 7;                    // features f4*4 .. f4*4+3
    int beg = rp[v], end = rp[v + 1];
    float4 s0 = make_float4(0.f, 0.f, 0.f, 0.f);
    float4 s1 = make_float4(0.f, 0.f, 0.f, 0.f);
    if (slot == 0)                        // self loop
        s0 = *(const float4*)(h1s + (long long)v * 32 + f4 * 4);
    int i = beg + slot;
    for (; i + 4 < end; i += 8) {
        int u0 = col[i], u1 = col[i + 4];
        float4 a = *(const float4*)(h1s + (long long)u0 * 32 + f4 * 4);
        float4 b = *(const float4*)(h1s + (long long)u1 * 32 + f4 * 4);
        f4add(s0, a);
        f4add(s1, b);
    }
    if (i < end) {
        int u0 = col[i];
        float4 a = *(const float4*)(h1s + (long long)u0 * 32 + f4 * 4);
        f4add(s0, a);
    }
    f4add(s0, s1);
    // reduce across the 4 slots (lanes xor 8, 16 — stays within 32-group)
    s0.x += __shfl_xor(s0.x, 8);  s0.y += __shfl_xor(s0.y, 8);
    s0.z += __shfl_xor(s0.z, 8);  s0.w += __shfl_xor(s0.w, 8);
    s0.x += __shfl_xor(s0.x, 16); s0.y += __shfl_xor(s0.y, 16);
    s0.z += __shfl_xor(s0.z, 16); s0.w += __shfl_xor(s0.w, 16);
    if (slot == 0) {
        float dv = dinv[v];
        float4 bb = *(const float4*)(b1 + f4 * 4);
        float4 r;
        r.x = dv * s0.x + bb.x; r.x = r.x > 0.f ? r.x : 0.f;
        r.y = dv * s0.y + bb.y; r.y = r.y > 0.f ? r.y : 0.f;
        r.z = dv * s0.z + bb.z; r.z = r.z > 0.f ? r.z : 0.f;
        r.w = dv * s0.w + bb.w; r.w = r.w > 0.f ? r.w : 0.f;
        *(float4*)(out1 + (long long)v * 32 + f4 * 4) = r;   // 8 lanes x 16B = 128B
    }
}

// ---- proj2: h2s[v] = (out1[v] @ W2) * dinv[v]   (32 -> 16) ----
__global__ void k_proj2(const float* __restrict__ out1, const float* __restrict__ W2,
                        const float* __restrict__ dinv, float* __restrict__ h2s, int N) {
    __shared__ float w[32 * 16];
    for (int i = threadIdx.x; i < 32 * 16; i += TPB) w[i] = W2[i];
    __syncthreads();
    int t = blockIdx.x * TPB + threadIdx.x;
    int v = t >> 4, f = t & 15;
    if (v >= N) return;
    const float4* xr = (const float4*)(out1 + (long long)v * 32);
    float acc = 0.f;
#pragma unroll
    for (int k4 = 0; k4 < 8; k4++) {
        float4 xv = xr[k4];
        int k = k4 * 4;
        acc = fmaf(xv.x, w[(k + 0) * 16 + f], acc);
        acc = fmaf(xv.y, w[(k + 1) * 16 + f], acc);
        acc = fmaf(xv.z, w[(k + 2) * 16 + f], acc);
        acc = fmaf(xv.w, w[(k + 3) * 16 + f], acc);
    }
    h2s[(long long)v * 16 + f] = acc * dinv[v];
}

// ---- gather2 + relu + final dot with Wl, bias bl ----
// 32 lanes/node = 8 neighbor-slots x 4 float4-lanes -> 16 row-loads in flight/wave
__global__ void k_gather2(const float* __restrict__ h2s, const int* __restrict__ col,
                          const int* __restrict__ rp, const float* __restrict__ dinv,
                          const float* __restrict__ b2, const float* __restrict__ Wl,
                          const float* __restrict__ bl, float* __restrict__ out, int N) {
    int t = blockIdx.x * TPB + threadIdx.x;
    int v = t >> 5;
    if (v >= N) return;
    int l32 = threadIdx.x & 31;
    int slot = l32 >> 2;                 // 0..7
    int f4 = l32 & 3;                    // features f4*4 .. f4*4+3
    int beg = rp[v], end = rp[v + 1];
    float4 s = make_float4(0.f, 0.f, 0.f, 0.f);
    if (slot == 0)                        // self loop
        s = *(const float4*)(h2s + (long long)v * 16 + f4 * 4);
    for (int i = beg + slot; i < end; i += 8) {
        int u = col[i];
        float4 a = *(const float4*)(h2s + (long long)u * 16 + f4 * 4);
        f4add(s, a);
    }
    // reduce across the 8 slots (lanes xor 4, 8, 16)
    s.x += __shfl_xor(s.x, 4);  s.y += __shfl_xor(s.y, 4);
    s.z += __shfl_xor(s.z, 4);  s.w += __shfl_xor(s.w, 4);
    s.x += __shfl_xor(s.x, 8);  s.y += __shfl_xor(s.y, 8);
    s.z += __shfl_xor(s.z, 8);  s.w += __shfl_xor(s.w, 8);
    s.x += __shfl_xor(s.x, 16); s.y += __shfl_xor(s.y, 16);
    s.z += __shfl_xor(s.z, 16); s.w += __shfl_xor(s.w, 16);
    if (slot == 0) {
        float dv = dinv[v];
        float4 bb = *(const float4*)(b2 + f4 * 4);
        float4 wl = *(const float4*)(Wl + f4 * 4);
        float rx = dv * s.x + bb.x; rx = rx > 0.f ? rx : 0.f;
        float ry = dv * s.y + bb.y; ry = ry > 0.f ? ry : 0.f;
        float rz = dv * s.z + bb.z; rz = rz > 0.f ? rz : 0.f;
        float rw = dv * s.w + bb.w; rw = rw > 0.f ? rw : 0.f;
        float p = rx * wl.x + ry * wl.y + rz * wl.z + rw * wl.w;
        p += __shfl_xor(p, 1);
        p += __shfl_xor(p, 2);
        if (f4 == 0) out[v] = p + bl[0];
    }
}

// ---------------------------------------------------------------------------
extern "C" void kernel_launch(void* const* d_in, const int* in_sizes, int n_in,
                              void* d_out, int out_size, void* d_ws, size_t ws_size,
                              hipStream_t stream) {
    const float* x    = (const float*)d_in[0];
    const int*   edges= (const int*)d_in[1];     // int32 or int64(low-word) — autodetected
    const float* W1   = (const float*)d_in[2];
    const float* b1   = (const float*)d_in[3];
    const float* W2   = (const float*)d_in[4];
    const float* b2   = (const float*)d_in[5];
    const float* Wl   = (const float*)d_in[6];
    const float* bl   = (const float*)d_in[7];
    float* out = (float*)d_out;

    const int       N = in_sizes[0] / 128;          // 100000
    const long long E = (long long)in_sizes[1] / 2; // 3200000
    const int      NB = (N + TPB - 1) / TPB;        // 391  (<=512 for scan_top)
    const int   NHIST = BKT * NBLK;                 // 65536
    const int    NB_H = NHIST / TPB;                // 256  (<=512 for scan_top)

    // workspace layout (256B aligned slices); tmp aliases h1s region
    char* ws = (char*)d_ws;
    size_t off = 0;
    auto carve = [&](size_t bytes) { void* p = ws + off; off = (off + bytes + 255) & ~(size_t)255; return p; };
    int*   deg     = (int*)  carve((size_t)N * 4);
    float* dinv    = (float*)carve((size_t)N * 4);
    int*   row_ptr = (int*)  carve((size_t)(N + 1) * 4);
    int*   fill    = (int*)  carve((size_t)N * 4);
    int*   partial = (int*)  carve((size_t)(NB + 1) * 4);
    int*   partialH= (int*)  carve((size_t)(NB_H + 1) * 4);
    int*   hist    = (int*)  carve((size_t)NHIST * 4);
    int*   histoff = (int*)  carve((size_t)(NHIST + 1) * 4);
    int*   col     = (int*)  carve((size_t)E * 4);
    float* unionA  = (float*)carve((size_t)N * 64 * 4);  // h1s(32)+out1(32) / packed tmp(E)
    float* h2s     = (float*)carve((size_t)N * 16 * 4);
    (void)ws_size; // total ~47 MB

    float*        h1s  = unionA;                  // N*32 floats
    float*        out1 = unionA + (size_t)N * 32;
    unsigned int* tmp  = (unsigned int*)unionA;   // E u32 (12.8MB <= N*32*4), dead before proj1

    // ---- binned CSR build ----
    hipLaunchKernelGGL(k_hist, dim3(NBLK), dim3(TPB), 0, stream, edges, hist, E);
    hipLaunchKernelGGL(k_scan_partial, dim3(NB_H), dim3(TPB), 0, stream, hist, partialH, NHIST, (float*)nullptr);
    hipLaunchKernelGGL(k_scan_top, dim3(1), dim3(512), 0, stream, partialH, NB_H);
    hipLaunchKernelGGL(k_scan_write, dim3(NB_H), dim3(TPB), 0, stream, hist, partialH, histoff, (int*)nullptr, NHIST, NB_H);
    hipLaunchKernelGGL(k_reorder, dim3(NBLK), dim3(TPB), 0, stream, edges, histoff, tmp, E);
    hipMemsetAsync(deg, 0, (size_t)N * 4, stream);
    hipLaunchKernelGGL(k_count2, dim3(NBLK), dim3(TPB), 0, stream, tmp, histoff, deg, E);
    hipLaunchKernelGGL(k_scan_partial, dim3(NB), dim3(TPB), 0, stream, deg, partial, N, dinv);
    hipLaunchKernelGGL(k_scan_top, dim3(1), dim3(512), 0, stream, partial, NB);
    hipLaunchKernelGGL(k_scan_write, dim3(NB), dim3(TPB), 0, stream, deg, partial, row_ptr, fill, N, NB);
    hipLaunchKernelGGL(k_scatter2, dim3(NBLK), dim3(TPB), 0, stream, tmp, histoff, fill, col, E);
    // ---- layer 1 (h1s/out1 reuse tmp region — tmp dead after scatter2) ----
    hipLaunchKernelGGL(k_proj1, dim3((N * 32 + TPB - 1) / TPB), dim3(TPB), 0, stream, x, W1, dinv, h1s, N);
    hipLaunchKernelGGL(k_gather1, dim3((N * 32 + TPB - 1) / TPB), dim3(TPB), 0, stream, h1s, col, row_ptr, dinv, b1, out1, N);
    // ---- layer 2 + head ----
    hipLaunchKernelGGL(k_proj2, dim3((N * 16 + TPB - 1) / TPB), dim3(TPB), 0, stream, out1, W2, dinv, h2s, N);
    hipLaunchKernelGGL(k_gather2, dim3((N * 32 + TPB - 1) / TPB), dim3(TPB), 0, stream, h2s, col, row_ptr, dinv, b2, Wl, bl, out, N);
}

// Round 5
// 356.980 us; speedup vs baseline: 2.3348x; 1.4624x over previous
//
#include <hip/hip_runtime.h>
#include <stdint.h>

// ---------------------------------------------------------------------------
// SimpleGNN_2Layer: 2-layer GCN (PyG GCNConv semantics) on MI355X.
// Round 5: kill scatter2's 124MB write-amp (113us). One block per 1024-node
// bucket sorts its own edges: LDS degree count -> LDS scan -> col placement
// within a 131KB window that lives in one XCD L2 until lines are full.
// Replaces count2 + deg-scan(3)+memset+fill + scatter2 with one kernel.
// ---------------------------------------------------------------------------

#define TPB 256
#define NBLK 512                // chunks for hist/reorder (runs ~64 edges = 256B)
#define BKT_SHIFT 10            // 1024 nodes per bucket
#define BKT_NODES 1024
#define MAXBKT 128
#define SRC_BITS 17
#define SRC_MASK 0x1FFFF

__device__ __forceinline__ int edge_at(const int* __restrict__ e, long long idx, int is64) {
    return e[is64 ? (2 * idx) : idx];            // low word holds value (<2^17)
}

// per-block edge dtype detect: int64 => odd 32-bit words of first 64 entries all 0
#define DETECT_IS64(edges)                                            \
    __shared__ int s_is64;                                            \
    if (threadIdx.x < 64) {                                           \
        int v_ = (edges)[2 * threadIdx.x + 1];                        \
        unsigned long long m_ = __ballot(v_ != 0);                    \
        if (threadIdx.x == 0) s_is64 = (m_ == 0ULL) ? 1 : 0;          \
    }

__device__ __forceinline__ void f4add(float4& a, const float4 b) {
    a.x += b.x; a.y += b.y; a.z += b.z; a.w += b.w;
}

// ---- pass A: per-chunk bucket histogram, bucket-major output ----
__global__ void k_hist(const int* __restrict__ edges, int* __restrict__ hist,
                       long long E, int nbkt) {
    __shared__ int cnt[MAXBKT];
    DETECT_IS64(edges);
    if (threadIdx.x < nbkt) cnt[threadIdx.x] = 0;
    __syncthreads();
    const int is64 = s_is64;
    const long long chunk = (E + NBLK - 1) / NBLK;
    const long long beg = (long long)blockIdx.x * chunk;
    const long long end = (beg + chunk < E) ? beg + chunk : E;
    for (long long e = beg + threadIdx.x; e < end; e += blockDim.x) {
        int d = edge_at(edges, E + e, is64);
        atomicAdd(&cnt[d >> BKT_SHIFT], 1);
    }
    __syncthreads();
    if (threadIdx.x < nbkt) hist[threadIdx.x * NBLK + blockIdx.x] = cnt[threadIdx.x];
}

// ---- pass B: reorder edges into bucket-major packed tmp (dlocal<<17|src) ----
__global__ void k_reorder(const int* __restrict__ edges, const int* __restrict__ histoff,
                          unsigned int* __restrict__ tmp, long long E, int nbkt) {
    __shared__ int off[MAXBKT];
    DETECT_IS64(edges);
    if (threadIdx.x < nbkt) off[threadIdx.x] = histoff[threadIdx.x * NBLK + blockIdx.x];
    __syncthreads();
    const int is64 = s_is64;
    const long long chunk = (E + NBLK - 1) / NBLK;
    const long long beg = (long long)blockIdx.x * chunk;
    const long long end = (beg + chunk < E) ? beg + chunk : E;
    for (long long e = beg + threadIdx.x; e < end; e += blockDim.x) {
        int s = edge_at(edges, e, is64);
        int d = edge_at(edges, E + e, is64);
        int pos = atomicAdd(&off[d >> BKT_SHIFT], 1);
        tmp[pos] = ((unsigned int)(d & (BKT_NODES - 1)) << SRC_BITS) | (unsigned int)s;
    }
}

// ---- generic scan step 1: per-block sums ----
__global__ void k_scan_partial(const int* __restrict__ cnt, int* __restrict__ partial, int N) {
    __shared__ int lds[TPB];
    int i = blockIdx.x * TPB + threadIdx.x;
    lds[threadIdx.x] = (i < N) ? cnt[i] : 0;
    __syncthreads();
    for (int s = TPB / 2; s > 0; s >>= 1) {
        if (threadIdx.x < s) lds[threadIdx.x] += lds[threadIdx.x + s];
        __syncthreads();
    }
    if (threadIdx.x == 0) partial[blockIdx.x] = lds[0];
}

// ---- generic scan step 2: exclusive scan of partials (NB <= 512) ----
__global__ void k_scan_top(int* __restrict__ partial, int NB) {
    __shared__ int lds[512];
    int t = threadIdx.x;
    int v = (t < NB) ? partial[t] : 0;
    lds[t] = v;
    __syncthreads();
    for (int off = 1; off < 512; off <<= 1) {
        int x = (t >= off) ? lds[t - off] : 0;
        __syncthreads();
        lds[t] += x;
        __syncthreads();
    }
    if (t < NB) partial[t] = lds[t] - v;   // exclusive
    if (t == 0) partial[NB] = lds[511];    // total
}

// ---- generic scan step 3: write exclusive scan (grid covers index N too) ----
__global__ void k_scan_write(const int* __restrict__ cnt, const int* __restrict__ partial,
                             int* __restrict__ outp, int N, int NB) {
    __shared__ int lds[TPB];
    int i = blockIdx.x * TPB + threadIdx.x;
    int v = (i < N) ? cnt[i] : 0;
    lds[threadIdx.x] = v;
    __syncthreads();
    for (int off = 1; off < TPB; off <<= 1) {
        int x = (threadIdx.x >= off) ? lds[threadIdx.x - off] : 0;
        __syncthreads();
        lds[threadIdx.x] += x;
        __syncthreads();
    }
    if (i < N) outp[i] = partial[blockIdx.x] + lds[threadIdx.x] - v;
    if (i == N) outp[N] = partial[NB];
}

// ---- per-bucket sort: deg count + scan + dinv/row_ptr + col placement ----
// One block (512 thr) owns one 1024-node bucket. tmp region [begI,endI) is the
// bucket's col range too (buckets are dst-major). 2nd tmp read hits L2.
__global__ void k_sortbucket(const unsigned int* __restrict__ tmp, const int* __restrict__ histoff,
                             float* __restrict__ dinv, int* __restrict__ row_ptr,
                             int* __restrict__ col, int N, long long E, int nbkt) {
    __shared__ int scnt[BKT_NODES];
    const int t = threadIdx.x;            // 0..511
    const int b = blockIdx.x;
    const int begI = histoff[b * NBLK];
    const int endI = histoff[(b + 1) * NBLK];   // histoff[nbkt*NBLK] == E
    scnt[t] = 0; scnt[t + 512] = 0;
    __syncthreads();
    // pass 1: count degrees within bucket
    for (int e = begI + t; e < endI; e += 512)
        atomicAdd(&scnt[tmp[e] >> SRC_BITS], 1);
    __syncthreads();
    const int c0 = scnt[t], c1 = scnt[t + 512];
    // inclusive Hillis-Steele scan over 1024 (2 elements/thread)
    for (int off = 1; off < BKT_NODES; off <<= 1) {
        int i0 = t, i1 = t + 512;
        int a0 = (i0 >= off) ? scnt[i0 - off] : 0;
        int a1 = (i1 >= off) ? scnt[i1 - off] : 0;
        __syncthreads();
        scnt[i0] += a0; scnt[i1] += a1;
        __syncthreads();
    }
    const int rp0 = begI + scnt[t] - c0;          // exclusive + bucket base
    const int rp1 = begI + scnt[t + 512] - c1;
    const int v0 = (b << BKT_SHIFT) + t;
    const int v1 = v0 + 512;
    if (v0 < N) { dinv[v0] = rsqrtf((float)(c0 + 1)); row_ptr[v0] = rp0; }
    if (v1 < N) { dinv[v1] = rsqrtf((float)(c1 + 1)); row_ptr[v1] = rp1; }
    if (b == nbkt - 1 && t == 0) row_ptr[N] = (int)E;
    __syncthreads();
    scnt[t] = rp0; scnt[t + 512] = rp1;           // running fill offsets
    __syncthreads();
    // pass 2: place src into col (131KB window, single block -> lines fill in L2)
    for (int e = begI + t; e < endI; e += 512) {
        unsigned int p = tmp[e];
        int pos = atomicAdd(&scnt[p >> SRC_BITS], 1);
        col[pos] = (int)(p & SRC_MASK);
    }
}

// ---- proj1: h1s[v] = (x[v] @ W1) * dinv[v]   (128 -> 32) ----
__global__ void k_proj1(const float* __restrict__ x, const float* __restrict__ W1,
                        const float* __restrict__ dinv, float* __restrict__ h1s, int N) {
    __shared__ float w[128 * 32];
    for (int i = threadIdx.x; i < 128 * 32; i += TPB) w[i] = W1[i];
    __syncthreads();
    int t = blockIdx.x * TPB + threadIdx.x;
    int v = t >> 5, f = t & 31;
    if (v >= N) return;
    const float4* xr = (const float4*)(x + (long long)v * 128);
    float acc = 0.f;
#pragma unroll
    for (int k4 = 0; k4 < 32; k4++) {
        float4 xv = xr[k4];                        // broadcast within 32-lane group
        int k = k4 * 4;
        acc = fmaf(xv.x, w[(k + 0) * 32 + f], acc);
        acc = fmaf(xv.y, w[(k + 1) * 32 + f], acc);
        acc = fmaf(xv.z, w[(k + 2) * 32 + f], acc);
        acc = fmaf(xv.w, w[(k + 3) * 32 + f], acc);
    }
    h1s[(long long)v * 32 + f] = acc * dinv[v];
}

// ---- gather1: out1[v] = relu(dinv[v]*(h1s[v] + sum_in h1s[u]) + b1) ----
// 32 lanes/node = 4 neighbor-slots x 8 float4-lanes; unroll 2 -> 16 lines in flight/wave
__global__ void k_gather1(const float* __restrict__ h1s, const int* __restrict__ col,
                          const int* __restrict__ rp, const float* __restrict__ dinv,
                          const float* __restrict__ b1, float* __restrict__ out1, int N) {
    int t = blockIdx.x * TPB + threadIdx.x;
    int v = t >> 5;
    if (v >= N) return;
    int l32 = threadIdx.x & 31;
    int slot = l32 >> 3;                 // 0..3
    int f4 = l32 & 7;                    // features f4*4 .. f4*4+3
    int beg = rp[v], end = rp[v + 1];
    float4 s0 = make_float4(0.f, 0.f, 0.f, 0.f);
    float4 s1 = make_float4(0.f, 0.f, 0.f, 0.f);
    if (slot == 0)                        // self loop
        s0 = *(const float4*)(h1s + (long long)v * 32 + f4 * 4);
    int i = beg + slot;
    for (; i + 4 < end; i += 8) {
        int u0 = col[i], u1 = col[i + 4];
        float4 a = *(const float4*)(h1s + (long long)u0 * 32 + f4 * 4);
        float4 b = *(const float4*)(h1s + (long long)u1 * 32 + f4 * 4);
        f4add(s0, a);
        f4add(s1, b);
    }
    if (i < end) {
        int u0 = col[i];
        float4 a = *(const float4*)(h1s + (long long)u0 * 32 + f4 * 4);
        f4add(s0, a);
    }
    f4add(s0, s1);
    s0.x += __shfl_xor(s0.x, 8);  s0.y += __shfl_xor(s0.y, 8);
    s0.z += __shfl_xor(s0.z, 8);  s0.w += __shfl_xor(s0.w, 8);
    s0.x += __shfl_xor(s0.x, 16); s0.y += __shfl_xor(s0.y, 16);
    s0.z += __shfl_xor(s0.z, 16); s0.w += __shfl_xor(s0.w, 16);
    if (slot == 0) {
        float dv = dinv[v];
        float4 bb = *(const float4*)(b1 + f4 * 4);
        float4 r;
        r.x = dv * s0.x + bb.x; r.x = r.x > 0.f ? r.x : 0.f;
        r.y = dv * s0.y + bb.y; r.y = r.y > 0.f ? r.y : 0.f;
        r.z = dv * s0.z + bb.z; r.z = r.z > 0.f ? r.z : 0.f;
        r.w = dv * s0.w + bb.w; r.w = r.w > 0.f ? r.w : 0.f;
        *(float4*)(out1 + (long long)v * 32 + f4 * 4) = r;   // 8 lanes x 16B = 128B
    }
}

// ---- proj2: h2s[v] = (out1[v] @ W2) * dinv[v]   (32 -> 16) ----
__global__ void k_proj2(const float* __restrict__ out1, const float* __restrict__ W2,
                        const float* __restrict__ dinv, float* __restrict__ h2s, int N) {
    __shared__ float w[32 * 16];
    for (int i = threadIdx.x; i < 32 * 16; i += TPB) w[i] = W2[i];
    __syncthreads();
    int t = blockIdx.x * TPB + threadIdx.x;
    int v = t >> 4, f = t & 15;
    if (v >= N) return;
    const float4* xr = (const float4*)(out1 + (long long)v * 32);
    float acc = 0.f;
#pragma unroll
    for (int k4 = 0; k4 < 8; k4++) {
        float4 xv = xr[k4];
        int k = k4 * 4;
        acc = fmaf(xv.x, w[(k + 0) * 16 + f], acc);
        acc = fmaf(xv.y, w[(k + 1) * 16 + f], acc);
        acc = fmaf(xv.z, w[(k + 2) * 16 + f], acc);
        acc = fmaf(xv.w, w[(k + 3) * 16 + f], acc);
    }
    h2s[(long long)v * 16 + f] = acc * dinv[v];
}

// ---- gather2 + relu + final dot with Wl, bias bl ----
// 32 lanes/node = 8 neighbor-slots x 4 float4-lanes -> 16 row-loads in flight/wave
__global__ void k_gather2(const float* __restrict__ h2s, const int* __restrict__ col,
                          const int* __restrict__ rp, const float* __restrict__ dinv,
                          const float* __restrict__ b2, const float* __restrict__ Wl,
                          const float* __restrict__ bl, float* __restrict__ out, int N) {
    int t = blockIdx.x * TPB + threadIdx.x;
    int v = t >> 5;
    if (v >= N) return;
    int l32 = threadIdx.x & 31;
    int slot = l32 >> 2;                 // 0..7
    int f4 = l32 & 3;                    // features f4*4 .. f4*4+3
    int beg = rp[v], end = rp[v + 1];
    float4 s = make_float4(0.f, 0.f, 0.f, 0.f);
    if (slot == 0)                        // self loop
        s = *(const float4*)(h2s + (long long)v * 16 + f4 * 4);
    for (int i = beg + slot; i < end; i += 8) {
        int u = col[i];
        float4 a = *(const float4*)(h2s + (long long)u * 16 + f4 * 4);
        f4add(s, a);
    }
    s.x += __shfl_xor(s.x, 4);  s.y += __shfl_xor(s.y, 4);
    s.z += __shfl_xor(s.z, 4);  s.w += __shfl_xor(s.w, 4);
    s.x += __shfl_xor(s.x, 8);  s.y += __shfl_xor(s.y, 8);
    s.z += __shfl_xor(s.z, 8);  s.w += __shfl_xor(s.w, 8);
    s.x += __shfl_xor(s.x, 16); s.y += __shfl_xor(s.y, 16);
    s.z += __shfl_xor(s.z, 16); s.w += __shfl_xor(s.w, 16);
    if (slot == 0) {
        float dv = dinv[v];
        float4 bb = *(const float4*)(b2 + f4 * 4);
        float4 wl = *(const float4*)(Wl + f4 * 4);
        float rx = dv * s.x + bb.x; rx = rx > 0.f ? rx : 0.f;
        float ry = dv * s.y + bb.y; ry = ry > 0.f ? ry : 0.f;
        float rz = dv * s.z + bb.z; rz = rz > 0.f ? rz : 0.f;
        float rw = dv * s.w + bb.w; rw = rw > 0.f ? rw : 0.f;
        float p = rx * wl.x + ry * wl.y + rz * wl.z + rw * wl.w;
        p += __shfl_xor(p, 1);
        p += __shfl_xor(p, 2);
        if (f4 == 0) out[v] = p + bl[0];
    }
}

// ---------------------------------------------------------------------------
extern "C" void kernel_launch(void* const* d_in, const int* in_sizes, int n_in,
                              void* d_out, int out_size, void* d_ws, size_t ws_size,
                              hipStream_t stream) {
    const float* x    = (const float*)d_in[0];
    const int*   edges= (const int*)d_in[1];     // int32 or int64(low-word) — autodetected
    const float* W1   = (const float*)d_in[2];
    const float* b1   = (const float*)d_in[3];
    const float* W2   = (const float*)d_in[4];
    const float* b2   = (const float*)d_in[5];
    const float* Wl   = (const float*)d_in[6];
    const float* bl   = (const float*)d_in[7];
    float* out = (float*)d_out;

    const int       N = in_sizes[0] / 128;          // 100000
    const long long E = (long long)in_sizes[1] / 2; // 3200000
    const int    nbkt = (N + BKT_NODES - 1) >> BKT_SHIFT;  // 98 (<=MAXBKT)
    const int      NH = nbkt * NBLK;                // 50176
    const int    NB_H = (NH + TPB - 1) / TPB;       // 196 (<=512 for scan_top)

    // workspace layout (256B aligned slices); tmp aliases h1s region
    char* ws = (char*)d_ws;
    size_t off = 0;
    auto carve = [&](size_t bytes) { void* p = ws + off; off = (off + bytes + 255) & ~(size_t)255; return p; };
    float* dinv    = (float*)carve((size_t)N * 4);
    int*   row_ptr = (int*)  carve((size_t)(N + 1) * 4);
    int*   partialH= (int*)  carve((size_t)(NB_H + 1) * 4);
    int*   hist    = (int*)  carve((size_t)NH * 4);
    int*   histoff = (int*)  carve((size_t)(NH + 1) * 4);
    int*   col     = (int*)  carve((size_t)E * 4);
    float* unionA  = (float*)carve((size_t)N * 64 * 4);  // h1s(32)+out1(32) / packed tmp(E)
    float* h2s     = (float*)carve((size_t)N * 16 * 4);
    (void)ws_size; // total ~46 MB

    float*        h1s  = unionA;                  // N*32 floats
    float*        out1 = unionA + (size_t)N * 32;
    unsigned int* tmp  = (unsigned int*)unionA;   // E u32 (= N*32*4 bytes), dead before proj1

    // ---- binned CSR build ----
    hipLaunchKernelGGL(k_hist, dim3(NBLK), dim3(TPB), 0, stream, edges, hist, E, nbkt);
    hipLaunchKernelGGL(k_scan_partial, dim3(NB_H), dim3(TPB), 0, stream, hist, partialH, NH);
    hipLaunchKernelGGL(k_scan_top, dim3(1), dim3(512), 0, stream, partialH, NB_H);
    hipLaunchKernelGGL(k_scan_write, dim3(NB_H + 1), dim3(TPB), 0, stream, hist, partialH, histoff, NH, NB_H);
    hipLaunchKernelGGL(k_reorder, dim3(NBLK), dim3(TPB), 0, stream, edges, histoff, tmp, E, nbkt);
    hipLaunchKernelGGL(k_sortbucket, dim3(nbkt), dim3(512), 0, stream, tmp, histoff, dinv, row_ptr, col, N, E, nbkt);
    // ---- layer 1 (h1s/out1 reuse tmp region — tmp dead after sortbucket) ----
    hipLaunchKernelGGL(k_proj1, dim3((N * 32 + TPB - 1) / TPB), dim3(TPB), 0, stream, x, W1, dinv, h1s, N);
    hipLaunchKernelGGL(k_gather1, dim3((N * 32 + TPB - 1) / TPB), dim3(TPB), 0, stream, h1s, col, row_ptr, dinv, b1, out1, N);
    // ---- layer 2 + head ----
    hipLaunchKernelGGL(k_proj2, dim3((N * 16 + TPB - 1) / TPB), dim3(TPB), 0, stream, out1, W2, dinv, h2s, N);
    hipLaunchKernelGGL(k_gather2, dim3((N * 32 + TPB - 1) / TPB), dim3(TPB), 0, stream, h2s, col, row_ptr, dinv, b2, Wl, bl, out, N);
}